// Round 3
// baseline (118.256 us; speedup 1.0000x reference)
//
#include <hip/hip_runtime.h>
#include <hip/hip_bf16.h>

typedef __bf16 bf16_t;
typedef bf16_t bf16x8 __attribute__((ext_vector_type(8)));
typedef float  f32x4  __attribute__((ext_vector_type(4)));

static constexpr int Nn = 8, Cc = 512, Hi = 32, Wi = 32, Oo = 512;
static constexpr int HO = 28, WO = 28;
static constexpr int M_ROWS = Nn * Hi * Wi;  // 8192

__device__ __forceinline__ float bf2f(unsigned short u) {
  union { unsigned int i; float f; } v; v.i = ((unsigned int)u) << 16; return v.f;
}
__device__ __forceinline__ unsigned short f2bf(float f) {
  union { float f; unsigned int u; } v; v.f = f;
  unsigned int u = v.u;
  return (unsigned short)((u + 0x7fffu + ((u >> 16) & 1u)) >> 16);  // RNE
}

// ---------- dtype detector: 1 = bf16 inputs, 0 = fp32 inputs ----------
// bf16 N(0,1) words have bits[7..14] (= bf16 exponent of low element) in
// [100,135] essentially always; fp32 words have uniform mantissa bits there.
__global__ void detect_kern(const unsigned int* __restrict__ xw, int* __restrict__ flag) {
  const int t = threadIdx.x;  // 64 threads
  const unsigned int u = xw[t];
  const int e = (int)((u >> 7) & 0xFFu);
  int c = (e >= 100 && e <= 135) ? 1 : 0;
  #pragma unroll
  for (int off = 32; off > 0; off >>= 1) c += __shfl_down(c, off, 64);
  if (t == 0) flag[0] = (c >= 40) ? 1 : 0;
}

__device__ __forceinline__ uint4 cvt8(const float* __restrict__ p) {
  const float4 f0 = *(const float4*)p;
  const float4 f1 = *(const float4*)(p + 4);
  uint4 r;
  r.x = (unsigned)f2bf(f0.x) | ((unsigned)f2bf(f0.y) << 16);
  r.y = (unsigned)f2bf(f0.z) | ((unsigned)f2bf(f0.w) << 16);
  r.z = (unsigned)f2bf(f1.x) | ((unsigned)f2bf(f1.y) << 16);
  r.w = (unsigned)f2bf(f1.z) | ((unsigned)f2bf(f1.w) << 16);
  return r;
}

// ---------------- GEMM: P[m,o] = bf16( sum_c X[m,c]*W[o,c] + bias[o] ) ----------------
#define BM 128
#define BN 128
#define BK 32

__global__ __launch_bounds__(256) void gemm_proj(
    const void* __restrict__ Xv, const void* __restrict__ Wv,
    const void* __restrict__ Bv, const int* __restrict__ flag,
    unsigned short* __restrict__ P)
{
  __shared__ bf16_t lA[BM * BK];
  __shared__ bf16_t lB[BN * BK];
  const bool isbf = flag[0] != 0;
  const int t    = threadIdx.x;
  const int bm   = blockIdx.x;   // 0..63
  const int bn   = blockIdx.y;   // 0..3
  const int lane = t & 63;
  const int wave = t >> 6;
  const int wm   = (wave >> 1) * 64;
  const int wn   = (wave & 1) * 64;

  f32x4 acc[4][4];
  #pragma unroll
  for (int a = 0; a < 4; a++)
    #pragma unroll
    for (int b = 0; b < 4; b++) acc[a][b] = (f32x4){0.f, 0.f, 0.f, 0.f};

  // staging map: thread t covers LDS row r0 = t>>2 (and r0+64), k-chunk (t&3)*8
  const int r0 = t >> 2;
  const int c0 = (t & 3) * 8;
  const size_t offA = (size_t)(bm * BM + r0) * Cc + c0;
  const size_t offB = (size_t)(bn * BN + r0) * Cc + c0;
  const bf16_t* Agb = (const bf16_t*)Xv + offA;
  const bf16_t* Bgb = (const bf16_t*)Wv + offB;
  const float*  Agf = (const float*)Xv + offA;
  const float*  Bgf = (const float*)Wv + offB;

  for (int k0 = 0; k0 < Cc; k0 += BK) {
    uint4 sa0, sa1, sb0, sb1;
    if (isbf) {
      sa0 = *(const uint4*)(Agb + k0);
      sa1 = *(const uint4*)(Agb + 64 * Cc + k0);
      sb0 = *(const uint4*)(Bgb + k0);
      sb1 = *(const uint4*)(Bgb + 64 * Cc + k0);
    } else {
      sa0 = cvt8(Agf + k0);
      sa1 = cvt8(Agf + 64 * Cc + k0);
      sb0 = cvt8(Bgf + k0);
      sb1 = cvt8(Bgf + 64 * Cc + k0);
    }
    __syncthreads();  // previous tile's fragment reads done before overwrite
    *(uint4*)&lA[t * 8]         = sa0;
    *(uint4*)&lA[(t + 256) * 8] = sa1;
    *(uint4*)&lB[t * 8]         = sb0;
    *(uint4*)&lB[(t + 256) * 8] = sb1;
    __syncthreads();

    const int kof = (lane >> 4) * 8;
    bf16x8 af[4], bfr[4];
    #pragma unroll
    for (int mt = 0; mt < 4; mt++)
      af[mt] = *(const bf16x8*)&lA[(wm + mt * 16 + (lane & 15)) * BK + kof];
    #pragma unroll
    for (int nt = 0; nt < 4; nt++)
      bfr[nt] = *(const bf16x8*)&lB[(wn + nt * 16 + (lane & 15)) * BK + kof];
    #pragma unroll
    for (int mt = 0; mt < 4; mt++)
      #pragma unroll
      for (int nt = 0; nt < 4; nt++)
        acc[mt][nt] = __builtin_amdgcn_mfma_f32_16x16x32_bf16(af[mt], bfr[nt], acc[mt][nt], 0, 0, 0);
  }

  // epilogue: C/D layout col=lane&15 (o), row=(lane>>4)*4+r (m)  [verified m89/m91]
  #pragma unroll
  for (int nt = 0; nt < 4; nt++) {
    const int col = bn * BN + wn + nt * 16 + (lane & 15);
    const float bias = isbf ? bf2f(((const unsigned short*)Bv)[col]) : ((const float*)Bv)[col];
    #pragma unroll
    for (int mt = 0; mt < 4; mt++) {
      #pragma unroll
      for (int r = 0; r < 4; r++) {
        const int row = bm * BM + wm + mt * 16 + (lane >> 4) * 4 + r;
        P[(size_t)row * Oo + col] = f2bf(acc[mt][nt][r] + bias);
      }
    }
  }
}

// ---------------- score: S[m] = sum_c X[m,c]*sw[c] + sb ----------------
__global__ __launch_bounds__(256) void score_kern(
    const void* __restrict__ Xv, const void* __restrict__ Swv,
    const void* __restrict__ Sbv, const int* __restrict__ flag,
    float* __restrict__ S)
{
  const bool isbf = flag[0] != 0;
  const int lane = threadIdx.x & 63;
  const int m = blockIdx.x * 4 + (threadIdx.x >> 6);
  float s = 0.f;
  if (isbf) {
    union { uint4 v; unsigned short us[8]; } xa, wa;
    xa.v = *(const uint4*)((const unsigned short*)Xv + (size_t)m * Cc + lane * 8);
    wa.v = *(const uint4*)((const unsigned short*)Swv + lane * 8);
    #pragma unroll
    for (int j = 0; j < 8; j++) s += bf2f(xa.us[j]) * bf2f(wa.us[j]);
  } else {
    const float* xf = (const float*)Xv + (size_t)m * Cc + lane * 8;
    const float* wf = (const float*)Swv + lane * 8;
    const float4 x0 = *(const float4*)xf, x1 = *(const float4*)(xf + 4);
    const float4 w0 = *(const float4*)wf, w1 = *(const float4*)(wf + 4);
    s = x0.x * w0.x + x0.y * w0.y + x0.z * w0.z + x0.w * w0.w
      + x1.x * w1.x + x1.y * w1.y + x1.z * w1.z + x1.w * w1.w;
  }
  #pragma unroll
  for (int off = 32; off > 0; off >>= 1) s += __shfl_down(s, off, 64);
  if (lane == 0) {
    const float sb = isbf ? bf2f(((const unsigned short*)Sbv)[0]) : ((const float*)Sbv)[0];
    S[m] = s + sb;
  }
}

// ---------------- combine: LN(25 scores) -> softmax -> weighted sum ----------------
__global__ __launch_bounds__(256) void combine_kern(
    const unsigned short* __restrict__ P, const float* __restrict__ S,
    const void* __restrict__ lnwv, const void* __restrict__ lnbv,
    const int* __restrict__ flag, void* __restrict__ outv)
{
  const bool isbf = flag[0] != 0;
  const int jg = blockIdx.x;   // 0..6
  const int i  = blockIdx.y;   // 0..27
  const int n  = blockIdx.z;   // 0..7
  const int j0 = jg * 4;
  const int t  = threadIdx.x;

  __shared__ float sc[5][8];    // score window rows i..i+4, cols j0..j0+7
  __shared__ float lw[4][25];   // softmax weights for jj=0..3
  __shared__ float lnwf[25], lnbf[25];

  if (t < 40) {
    const int ri = t >> 3, cj = t & 7;
    sc[ri][cj] = S[(n * Hi + i + ri) * Wi + (j0 + cj)];
  }
  if (t < 25) {
    lnwf[t] = isbf ? bf2f(((const unsigned short*)lnwv)[t]) : ((const float*)lnwv)[t];
    lnbf[t] = isbf ? bf2f(((const unsigned short*)lnbv)[t]) : ((const float*)lnbv)[t];
  }
  __syncthreads();

  {
    const int wv = t >> 6;     // which jj this wave handles
    const int kk = t & 63;
    if (kk < 25) {
      float mu = 0.f;
      #pragma unroll
      for (int q = 0; q < 25; q++) mu += sc[q / 5][wv + q % 5];
      mu *= (1.0f / 25.0f);
      float var = 0.f;
      #pragma unroll
      for (int q = 0; q < 25; q++) { const float d = sc[q / 5][wv + q % 5] - mu; var += d * d; }
      var *= (1.0f / 25.0f);
      const float rr = rsqrtf(var + 1e-5f);
      float scn[25];
      float mx = -1e30f;
      #pragma unroll
      for (int q = 0; q < 25; q++) {
        scn[q] = (sc[q / 5][wv + q % 5] - mu) * rr * lnwf[q] + lnbf[q];
        mx = fmaxf(mx, scn[q]);
      }
      float den = 0.f, mine = 0.f;
      #pragma unroll
      for (int q = 0; q < 25; q++) {
        const float e = __expf(scn[q] - mx);
        den += e;
        if (q == kk) mine = e;
      }
      lw[wv][kk] = mine / den;
    }
  }
  __syncthreads();

  // each thread: channels o=2t,2t+1 across 4 output columns; P is bf16
  float a0[4] = {0.f, 0.f, 0.f, 0.f}, a1[4] = {0.f, 0.f, 0.f, 0.f};
  const unsigned short* Pb = P + 2 * t;
  #pragma unroll
  for (int ki = 0; ki < 5; ki++) {
    const int rowb = (n * Hi + i + ki) * Wi + j0;
    #pragma unroll
    for (int col = 0; col < 8; col++) {
      const unsigned int v = *(const unsigned int*)(Pb + (size_t)(rowb + col) * Oo);
      const float vx = bf2f((unsigned short)(v & 0xFFFFu));
      const float vy = bf2f((unsigned short)(v >> 16));
      #pragma unroll
      for (int jj = 0; jj < 4; jj++) {
        const int kj = col - jj;
        if (kj >= 0 && kj < 5) {
          const float w_ = lw[jj][ki * 5 + kj];
          a0[jj] += vx * w_;
          a1[jj] += vy * w_;
        }
      }
    }
  }

  const size_t ob0 = (((size_t)n * Oo + 2 * t) * HO + i) * WO + j0;
  const size_t ob1 = ob0 + (size_t)HO * WO;
  if (isbf) {
    union { ushort4 v; unsigned short us[4]; } p0, p1;
    #pragma unroll
    for (int jj = 0; jj < 4; jj++) { p0.us[jj] = f2bf(a0[jj]); p1.us[jj] = f2bf(a1[jj]); }
    *(ushort4*)&((unsigned short*)outv)[ob0] = p0.v;
    *(ushort4*)&((unsigned short*)outv)[ob1] = p1.v;
  } else {
    float4 q0, q1;
    q0.x = a0[0]; q0.y = a0[1]; q0.z = a0[2]; q0.w = a0[3];
    q1.x = a1[0]; q1.y = a1[1]; q1.z = a1[2]; q1.w = a1[3];
    *(float4*)&((float*)outv)[ob0] = q0;
    *(float4*)&((float*)outv)[ob1] = q1;
  }
}

extern "C" void kernel_launch(void* const* d_in, const int* in_sizes, int n_in,
                              void* d_out, int out_size, void* d_ws, size_t ws_size,
                              hipStream_t stream) {
  const void* x   = d_in[0];
  const void* pw  = d_in[1];
  const void* pb  = d_in[2];
  const void* sw  = d_in[3];
  const void* sb  = d_in[4];
  const void* lnw = d_in[5];
  const void* lnb = d_in[6];

  int*   flag = (int*)d_ws;                                   // 256 B slot
  float* S    = (float*)((char*)d_ws + 256);                  // 8192 fp32 = 32 KiB
  unsigned short* P = (unsigned short*)((char*)d_ws + 256 + (size_t)M_ROWS * 4);  // 8 MiB

  detect_kern<<<1, 64, 0, stream>>>((const unsigned int*)x, flag);
  gemm_proj<<<dim3(M_ROWS / BM, Oo / BN), 256, 0, stream>>>(x, pw, pb, flag, P);
  score_kern<<<dim3(M_ROWS / 4), 256, 0, stream>>>(x, sw, sb, flag, S);
  combine_kern<<<dim3(WO / 4, HO, Nn), 256, 0, stream>>>(P, S, lnw, lnb, flag, d_out);
}

// Round 4
// 116.027 us; speedup vs baseline: 1.0192x; 1.0192x over previous
//
#include <hip/hip_runtime.h>

typedef __bf16 bf16_t;
typedef bf16_t bf16x8 __attribute__((ext_vector_type(8)));
typedef float  f32x4  __attribute__((ext_vector_type(4)));

#define GAS __attribute__((address_space(1)))
#define LAS __attribute__((address_space(3)))

static constexpr int Nn = 8, Cc = 512, Hi = 32, Wi = 32, Oo = 512;
static constexpr int HO = 28, WO = 28;
static constexpr int M_ROWS = Nn * Hi * Wi;  // 8192

__device__ __forceinline__ float bf2f(unsigned short u) {
  union { unsigned int i; float f; } v; v.i = ((unsigned int)u) << 16; return v.f;
}
__device__ __forceinline__ unsigned short f2bf(float f) {
  union { float f; unsigned int u; } v; v.f = f;
  unsigned int u = v.u;
  return (unsigned short)((u + 0x7fffu + ((u >> 16) & 1u)) >> 16);  // RNE
}
__device__ __forceinline__ uint4 pack8(float4 f0, float4 f1) {
  uint4 r;
  r.x = (unsigned)f2bf(f0.x) | ((unsigned)f2bf(f0.y) << 16);
  r.y = (unsigned)f2bf(f0.z) | ((unsigned)f2bf(f0.w) << 16);
  r.z = (unsigned)f2bf(f1.x) | ((unsigned)f2bf(f1.y) << 16);
  r.w = (unsigned)f2bf(f1.z) | ((unsigned)f2bf(f1.w) << 16);
  return r;
}

// ---------------- W fp32 -> bf16 ----------------
__global__ __launch_bounds__(256) void cvtw_kern(const float* __restrict__ W,
                                                 unsigned short* __restrict__ Wb) {
  const int idx = (blockIdx.x * 256 + threadIdx.x) * 8;
  const float4 f0 = *(const float4*)(W + idx);
  const float4 f1 = *(const float4*)(W + idx + 4);
  *(uint4*)(Wb + idx) = pack8(f0, f1);
}

// ---------------- score GEMV (fp32 exact) + X fp32 -> bf16 ----------------
__global__ __launch_bounds__(256) void score_cvt_kern(
    const float* __restrict__ X, const float* __restrict__ Sw,
    const float* __restrict__ Sb, unsigned short* __restrict__ Xb,
    float* __restrict__ S)
{
  const int lane = threadIdx.x & 63;
  const int m = blockIdx.x * 4 + (threadIdx.x >> 6);
  const float* xf = X + (size_t)m * Cc + lane * 8;
  const float* wf = Sw + lane * 8;
  const float4 x0 = *(const float4*)xf, x1 = *(const float4*)(xf + 4);
  const float4 w0 = *(const float4*)wf, w1 = *(const float4*)(wf + 4);
  *(uint4*)(Xb + (size_t)m * Cc + lane * 8) = pack8(x0, x1);
  float s = x0.x * w0.x + x0.y * w0.y + x0.z * w0.z + x0.w * w0.w
          + x1.x * w1.x + x1.y * w1.y + x1.z * w1.z + x1.w * w1.w;
  #pragma unroll
  for (int off = 32; off > 0; off >>= 1) s += __shfl_down(s, off, 64);
  if (lane == 0) S[m] = s + Sb[0];
}

// ---------------- GEMM: P[m,o] = bf16( sum_c Xb[m,c]*Wb[o,c] + bias[o] ) ----------------
#define BM 128
#define BN 64
#define BK 32

__global__ __launch_bounds__(256) void gemm_proj(
    const bf16_t* __restrict__ Xb, const bf16_t* __restrict__ Wb,
    const float* __restrict__ Bp, unsigned short* __restrict__ P)
{
  __shared__ bf16_t lA[BM * BK];   // 8 KiB
  __shared__ bf16_t lB[BN * BK];   // 4 KiB
  const int t    = threadIdx.x;
  const int bm   = blockIdx.x;   // 0..63
  const int bn   = blockIdx.y;   // 0..7
  const int lane = t & 63;
  const int wave = t >> 6;
  const int wm   = (wave >> 1) * 64;
  const int wn   = (wave & 1) * 32;

  f32x4 acc[4][2];
  #pragma unroll
  for (int a = 0; a < 4; a++)
    #pragma unroll
    for (int b = 0; b < 2; b++) acc[a][b] = (f32x4){0.f, 0.f, 0.f, 0.f};

  // staging map: thread t covers LDS row r0=t>>2 (and r0+64 for A), k-chunk (t&3)*8
  const int r0 = t >> 2;
  const int c0 = (t & 3) * 8;
  const bf16_t* Ag = Xb + (size_t)(bm * BM + r0) * Cc + c0;
  const bf16_t* Bg = Wb + (size_t)(bn * BN + r0) * Cc + c0;

  for (int k0 = 0; k0 < Cc; k0 += BK) {
    __syncthreads();  // previous tile's fragment reads done before overwrite
    __builtin_amdgcn_global_load_lds((const GAS void*)(Ag + k0),           (LAS void*)&lA[t * 8],         16, 0, 0);
    __builtin_amdgcn_global_load_lds((const GAS void*)(Ag + 64 * Cc + k0), (LAS void*)&lA[(t + 256) * 8], 16, 0, 0);
    __builtin_amdgcn_global_load_lds((const GAS void*)(Bg + k0),           (LAS void*)&lB[t * 8],         16, 0, 0);
    __syncthreads();  // drains vmcnt before s_barrier -> LDS writes visible

    const int kof = (lane >> 4) * 8;
    bf16x8 af[4], bfr[2];
    #pragma unroll
    for (int mt = 0; mt < 4; mt++)
      af[mt] = *(const bf16x8*)&lA[(wm + mt * 16 + (lane & 15)) * BK + kof];
    #pragma unroll
    for (int nt = 0; nt < 2; nt++)
      bfr[nt] = *(const bf16x8*)&lB[(wn + nt * 16 + (lane & 15)) * BK + kof];
    #pragma unroll
    for (int mt = 0; mt < 4; mt++)
      #pragma unroll
      for (int nt = 0; nt < 2; nt++)
        acc[mt][nt] = __builtin_amdgcn_mfma_f32_16x16x32_bf16(af[mt], bfr[nt], acc[mt][nt], 0, 0, 0);
  }

  // epilogue: C/D layout col=lane&15 (o), row=(lane>>4)*4+r (m)
  #pragma unroll
  for (int nt = 0; nt < 2; nt++) {
    const int col = bn * BN + wn + nt * 16 + (lane & 15);
    const float bias = Bp[col];
    #pragma unroll
    for (int mt = 0; mt < 4; mt++) {
      #pragma unroll
      for (int r = 0; r < 4; r++) {
        const int row = bm * BM + wm + mt * 16 + (lane >> 4) * 4 + r;
        P[(size_t)row * Oo + col] = f2bf(acc[mt][nt][r] + bias);
      }
    }
  }
}

// ---------------- combine: LN(25 scores) -> softmax -> weighted sum ----------------
// block = (i, n), 512 threads: thread -> (8-ch group, 4-j group)
__global__ __launch_bounds__(512) void combine_kern(
    const unsigned short* __restrict__ P, const float* __restrict__ S,
    const float* __restrict__ lnw, const float* __restrict__ lnb,
    float* __restrict__ out)
{
  const int i = blockIdx.x;   // 0..27
  const int n = blockIdx.y;   // 0..7
  const int t = threadIdx.x;

  __shared__ float sc[5][32];   // score rows i..i+4, all 32 cols
  __shared__ float lw[28][25];  // softmax weights per output col j

  if (t < 160) sc[t >> 5][t & 31] = S[(n * Hi + i + (t >> 5)) * Wi + (t & 31)];
  __syncthreads();

  if (t < 28) {
    const int j = t;
    float mu = 0.f;
    #pragma unroll
    for (int q = 0; q < 25; q++) mu += sc[q / 5][j + q % 5];
    mu *= (1.0f / 25.0f);
    float var = 0.f;
    #pragma unroll
    for (int q = 0; q < 25; q++) { const float d = sc[q / 5][j + q % 5] - mu; var += d * d; }
    var *= (1.0f / 25.0f);
    const float rr = rsqrtf(var + 1e-5f);
    float e[25], mx = -1e30f;
    #pragma unroll
    for (int q = 0; q < 25; q++) {
      e[q] = (sc[q / 5][j + q % 5] - mu) * rr * lnw[q] + lnb[q];
      mx = fmaxf(mx, e[q]);
    }
    float den = 0.f;
    #pragma unroll
    for (int q = 0; q < 25; q++) { e[q] = __expf(e[q] - mx); den += e[q]; }
    const float inv = 1.0f / den;
    #pragma unroll
    for (int q = 0; q < 25; q++) lw[j][q] = e[q] * inv;
  }
  __syncthreads();

  const int chg = t & 63;       // 8-channel group: ch = chg*8..chg*8+7
  const int jq  = t >> 6;       // 0..7; jq<7 handles j = jq*4..jq*4+3
  if (jq >= 7) return;
  const int c0 = jq * 4;

  float acc[4][8];
  #pragma unroll
  for (int a = 0; a < 4; a++)
    #pragma unroll
    for (int b = 0; b < 8; b++) acc[a][b] = 0.f;

  const unsigned short* Pb = P + chg * 8;
  #pragma unroll
  for (int col = 0; col < 8; col++) {
    const int c = c0 + col;
    float f[5][8];
    #pragma unroll
    for (int ki = 0; ki < 5; ki++) {
      const uint4 v = *(const uint4*)(Pb + (size_t)((n * Hi + i + ki) * Wi + c) * Oo);
      f[ki][0] = bf2f((unsigned short)(v.x & 0xFFFFu)); f[ki][1] = bf2f((unsigned short)(v.x >> 16));
      f[ki][2] = bf2f((unsigned short)(v.y & 0xFFFFu)); f[ki][3] = bf2f((unsigned short)(v.y >> 16));
      f[ki][4] = bf2f((unsigned short)(v.z & 0xFFFFu)); f[ki][5] = bf2f((unsigned short)(v.z >> 16));
      f[ki][6] = bf2f((unsigned short)(v.w & 0xFFFFu)); f[ki][7] = bf2f((unsigned short)(v.w >> 16));
    }
    #pragma unroll
    for (int jj = 0; jj < 4; jj++) {
      const int kj = col - jj;
      if (kj >= 0 && kj < 5) {
        #pragma unroll
        for (int ki = 0; ki < 5; ki++) {
          const float w_ = lw[c0 + jj][ki * 5 + kj];
          #pragma unroll
          for (int ch = 0; ch < 8; ch++) acc[jj][ch] += f[ki][ch] * w_;
        }
      }
    }
  }

  #pragma unroll
  for (int jj = 0; jj < 4; jj++)
    #pragma unroll
    for (int ch = 0; ch < 8; ch++)
      out[(((size_t)n * Oo + chg * 8 + ch) * HO + i) * WO + (c0 + jj)] = acc[jj][ch];
}

extern "C" void kernel_launch(void* const* d_in, const int* in_sizes, int n_in,
                              void* d_out, int out_size, void* d_ws, size_t ws_size,
                              hipStream_t stream) {
  const float* x   = (const float*)d_in[0];
  const float* pw  = (const float*)d_in[1];
  const float* pb  = (const float*)d_in[2];
  const float* sw  = (const float*)d_in[3];
  const float* sb  = (const float*)d_in[4];
  const float* lnw = (const float*)d_in[5];
  const float* lnb = (const float*)d_in[6];

  char* w = (char*)d_ws;
  float*          Sv = (float*)w;                                   // 32 KiB
  unsigned short* Xb = (unsigned short*)(w + 64 * 1024);            // 8 MiB
  unsigned short* Wb = (unsigned short*)(w + 64 * 1024 + (size_t)M_ROWS * Cc * 2);  // 512 KiB
  unsigned short* P  = (unsigned short*)(w + 64 * 1024 + (size_t)M_ROWS * Cc * 2 + (size_t)Oo * Cc * 2);  // 8 MiB

  cvtw_kern<<<dim3(Oo * Cc / (256 * 8)), 256, 0, stream>>>(pw, Wb);
  score_cvt_kern<<<dim3(M_ROWS / 4), 256, 0, stream>>>(x, sw, sb, Xb, Sv);
  gemm_proj<<<dim3(M_ROWS / BM, Oo / BN), 256, 0, stream>>>((const bf16_t*)Xb, (const bf16_t*)Wb, pb, P);
  combine_kern<<<dim3(HO, Nn), 512, 0, stream>>>(P, Sv, lnw, lnb, (float*)d_out);
}